// Round 10
// baseline (245.524 us; speedup 1.0000x reference)
//
#include <hip/hip_runtime.h>

#define N_NODES 50000
#define N_EDGES 800000

typedef __attribute__((ext_vector_type(8))) short short8;
typedef __attribute__((ext_vector_type(4))) float floatx4;

// float -> bf16 bits, round-to-nearest-even
static __device__ __forceinline__ unsigned short f2b(float f) {
    unsigned int u = __float_as_uint(f);
    unsigned int r = u + 0x7fffu + ((u >> 16) & 1u);
    return (unsigned short)(r >> 16);
}
static __device__ __forceinline__ unsigned int pk(float a, float b) {
    return (unsigned)f2b(a) | ((unsigned)f2b(b) << 16);
}
static __device__ __forceinline__ float blo(unsigned int u) {
    return __uint_as_float(u << 16);
}
static __device__ __forceinline__ float bhi(unsigned int u) {
    return __uint_as_float(u & 0xffff0000u);
}

// accumulate 4 bf16x8 rows into 8 fp32 lanes (same add tree as verified vers)
static __device__ __forceinline__ void acc4(float* f, uint4 v0, uint4 v1,
                                            uint4 v2, uint4 v3) {
    f[0] += (blo(v0.x) + blo(v1.x)) + (blo(v2.x) + blo(v3.x));
    f[1] += (bhi(v0.x) + bhi(v1.x)) + (bhi(v2.x) + bhi(v3.x));
    f[2] += (blo(v0.y) + blo(v1.y)) + (blo(v2.y) + blo(v3.y));
    f[3] += (bhi(v0.y) + bhi(v1.y)) + (bhi(v2.y) + bhi(v3.y));
    f[4] += (blo(v0.z) + blo(v1.z)) + (blo(v2.z) + blo(v3.z));
    f[5] += (bhi(v0.z) + bhi(v1.z)) + (bhi(v2.z) + bhi(v3.z));
    f[6] += (blo(v0.w) + blo(v1.w)) + (blo(v2.w) + blo(v3.w));
    f[7] += (bhi(v0.w) + bhi(v1.w)) + (bhi(v2.w) + bhi(v3.w));
}

// ---------------------------------------------------------------------------
// CSR build, segments padded to x4 with sentinel zero-row N_NODES.
// R10: rank[] eliminated — hist is a pure histogram; fill takes its slot
// directly via atomicAdd on a cursor copy of the segment bases (same one
// atomic per edge, minus a full 800k-element array write+read pass).
// Within-segment edge order is nondeterministic — it already was (hist_rank
// atomic race), and bf16 accumulation passes at absmax 0.5 regardless.
// offpd = (off<<10 | padded_deg).
// ---------------------------------------------------------------------------
__global__ void hist_kernel(const int* __restrict__ dst, int* __restrict__ deg,
                            int n) {
    int i = blockIdx.x * blockDim.x + threadIdx.x;
    if (i < n) atomicAdd(&deg[dst[i]], 1);
}

__global__ __launch_bounds__(1024) void offsets_kernel(
    const int* __restrict__ deg, int* __restrict__ offpd,
    int* __restrict__ cursor, int* __restrict__ gcount,
    unsigned short* __restrict__ nbr, int n) {
    __shared__ int s[1024];
    __shared__ int base;
    const int tid = threadIdx.x;
    const int i = blockIdx.x * 1024 + tid;
    const int d = (i < n) ? deg[i] : 0;
    const int pd = (d + 3) & ~3;
    s[tid] = pd;
    __syncthreads();
    for (int o = 1; o < 1024; o <<= 1) {
        int t = (tid >= o) ? s[tid - o] : 0;
        __syncthreads();
        s[tid] += t;
        __syncthreads();
    }
    if (tid == 1023) base = atomicAdd(gcount, s[1023]);
    __syncthreads();
    const int excl = base + s[tid] - pd;
    if (i < n) {
        offpd[i] = (excl << 10) | pd;
        cursor[i] = excl;
        for (int k = d; k < pd; ++k) nbr[excl + k] = (unsigned short)N_NODES;
    }
}

// Edge scatter: slot taken directly from the per-node cursor.
__global__ void fill_kernel(const int* __restrict__ src,
                            const int* __restrict__ dst,
                            int* __restrict__ cursor,
                            unsigned short* __restrict__ nbr, int n) {
    int i = blockIdx.x * blockDim.x + threadIdx.x;
    if (i < n) {
        const int pos = atomicAdd(&cursor[dst[i]], 1);
        nbr[pos] = (unsigned short)src[i];
    }
}

// ---------------------------------------------------------------------------
// Fused prep: weight transpose->bf16 [N][K] + x fp32->bf16 + deg/gcount
// zeroing + zero sentinel rows of xb and h (row N_NODES of each table).
// ---------------------------------------------------------------------------
__global__ __launch_bounds__(256) void prep_kernel(
    const float* __restrict__ W1a, const float* __restrict__ W1b,
    const float* __restrict__ W2a, const float* __restrict__ W2b,
    const float* __restrict__ x, unsigned short* __restrict__ W1aT,
    unsigned short* __restrict__ W1bT, unsigned short* __restrict__ W2aT,
    unsigned short* __restrict__ W2bT, unsigned short* __restrict__ xb,
    unsigned short* __restrict__ h, int* __restrict__ deg,
    int* __restrict__ gcount) {
    int i = blockIdx.x * 256 + threadIdx.x;
    if (i < 8192) {                       // W1a [64][128] -> [128][64]
        int n = i >> 6, k = i & 63;
        W1aT[i] = f2b(W1a[k * 128 + n]);
    } else if (i < 24576) {               // W1b [128][128] -> [128][128]
        int j = i - 8192, n = j >> 7, k = j & 127;
        W1bT[j] = f2b(W1b[k * 128 + n]);
    } else if (i < 40960) {               // W2a [128][128] -> [128][128]
        int j = i - 24576, n = j >> 7, k = j & 127;
        W2aT[j] = f2b(W2a[k * 128 + n]);
    } else if (i < 49152) {               // W2b [128][64] -> [64][128]
        int j = i - 40960, n = j >> 7, k = j & 127;
        W2bT[j] = f2b(W2b[k * 64 + n]);
    } else if (i < 49152 + N_NODES * 16) {  // x convert: float4 -> 4x bf16
        int j = i - 49152;
        float4 v = ((const float4*)x)[j];
        uint2 o;
        o.x = pk(v.x, v.y);
        o.y = pk(v.z, v.w);
        ((uint2*)xb)[j] = o;
    } else if (i < 49152 + N_NODES * 16 + N_NODES) {  // zero deg (+gcount)
        int j = i - (49152 + N_NODES * 16);
        deg[j] = 0;
        if (j == 0) *gcount = 0;
    } else {  // zero sentinel rows: xb row N (128B), h row N (256B)
        int j = i - (49152 + N_NODES * 16 + N_NODES);
        uint4 z = {0u, 0u, 0u, 0u};
        if (j < 8)
            ((uint4*)(xb + (size_t)N_NODES * 64))[j] = z;
        else if (j < 24)
            ((uint4*)(h + (size_t)N_NODES * 128))[j - 8] = z;
    }
}

// ---------------------------------------------------------------------------
// Fused GIN layer (R7-verified geometry, unchanged). LPR = DIN/8 lanes per
// row, each lane one uint4 (16B); indices as aligned uint2 (segments padded
// x4); 8 edges in flight per group. One offpd read gives base+length.
// MLP: ROWS=32 -> 2x2 wave split; ROWS=16 -> 1x4 (N-quarters).
// ---------------------------------------------------------------------------
template <int DIN, int DH, int DOUT, bool OUT_BF16>
__global__ __launch_bounds__(256) void gin_fused_kernel(
    const unsigned short* __restrict__ xin, const int* __restrict__ offpd,
    const unsigned short* __restrict__ nbr,
    const unsigned short* __restrict__ WaT, const float* __restrict__ ba,
    const unsigned short* __restrict__ WbT, const float* __restrict__ bb,
    void* __restrict__ outp, int n_rows) {
    constexpr int LPR = DIN / 8;     // lanes per row (uint4 = 8 bf16 each)
    constexpr int ROWS = 256 / LPR;  // rows per block (32 or 16)
    constexpr int SA = DIN + 16;
    constexpr int SH = DH + 16;
    __shared__ __attribute__((aligned(16))) unsigned short tA[ROWS * SA];
    __shared__ __attribute__((aligned(16))) unsigned short hidA[ROWS * SH];

    const int tid = threadIdx.x;
    const int row0 = blockIdx.x * ROWS;
    const int grp = tid / LPR;  // one row per group
    const int c = tid % LPR;
    const int node = row0 + grp;

    // ---- gather phase ----
    float f[8] = {0.f, 0.f, 0.f, 0.f, 0.f, 0.f, 0.f, 0.f};
    const uint4* xr = (const uint4*)xin;
    if (node < n_rows) {
        const uint4 a = xr[(size_t)node * LPR + c];
        f[0] = blo(a.x); f[1] = bhi(a.x);
        f[2] = blo(a.y); f[3] = bhi(a.y);
        f[4] = blo(a.z); f[5] = bhi(a.z);
        f[6] = blo(a.w); f[7] = bhi(a.w);
        const int v = offpd[node];
        const int lo = v >> 10;
        const int hi = lo + (v & 1023);
        int j = lo;
        for (; j + 8 <= hi; j += 8) {
            const uint2 i0 = *(const uint2*)&nbr[j];
            const uint2 i1 = *(const uint2*)&nbr[j + 4];
            const int s0 = i0.x & 0xffff, s1 = i0.x >> 16;
            const int s2 = i0.y & 0xffff, s3 = i0.y >> 16;
            const int s4 = i1.x & 0xffff, s5 = i1.x >> 16;
            const int s6 = i1.y & 0xffff, s7 = i1.y >> 16;
            const uint4 v0 = xr[(size_t)s0 * LPR + c];
            const uint4 v1 = xr[(size_t)s1 * LPR + c];
            const uint4 v2 = xr[(size_t)s2 * LPR + c];
            const uint4 v3 = xr[(size_t)s3 * LPR + c];
            const uint4 v4 = xr[(size_t)s4 * LPR + c];
            const uint4 v5 = xr[(size_t)s5 * LPR + c];
            const uint4 v6 = xr[(size_t)s6 * LPR + c];
            const uint4 v7 = xr[(size_t)s7 * LPR + c];
            acc4(f, v0, v1, v2, v3);
            acc4(f, v4, v5, v6, v7);
        }
        if (j < hi) {  // exactly one 4-edge chunk remains (padding)
            const uint2 i0 = *(const uint2*)&nbr[j];
            const int s0 = i0.x & 0xffff, s1 = i0.x >> 16;
            const int s2 = i0.y & 0xffff, s3 = i0.y >> 16;
            const uint4 v0 = xr[(size_t)s0 * LPR + c];
            const uint4 v1 = xr[(size_t)s1 * LPR + c];
            const uint4 v2 = xr[(size_t)s2 * LPR + c];
            const uint4 v3 = xr[(size_t)s3 * LPR + c];
            acc4(f, v0, v1, v2, v3);
        }
    }
    uint4 o;
    o.x = pk(f[0], f[1]);
    o.y = pk(f[2], f[3]);
    o.z = pk(f[4], f[5]);
    o.w = pk(f[6], f[7]);
    *(uint4*)&tA[grp * SA + c * 8] = o;
    __syncthreads();

    // ---- MLP phase ----
    constexpr int MT = ROWS / 16;     // M tiles (2 or 1)
    constexpr int NSPLIT = 4 / MT;    // N split across waves (2 or 4)
    const int lane = tid & 63;
    const int wv = tid >> 6;
    const int wm = wv % MT;
    const int wn = wv / MT;
    const int quad = lane >> 4;
    const int l16 = lane & 15;
    const int m0 = wm * 16;

    short8 a1[DIN / 32];
#pragma unroll
    for (int kk = 0; kk < DIN / 32; ++kk)
        a1[kk] = *(const short8*)&tA[(m0 + l16) * SA + kk * 32 + quad * 8];
#pragma unroll
    for (int nt = 0; nt < DH / (16 * NSPLIT); ++nt) {
        const int col = wn * (DH / NSPLIT) + nt * 16 + l16;
        floatx4 acc = {0.f, 0.f, 0.f, 0.f};
#pragma unroll
        for (int kk = 0; kk < DIN / 32; ++kk) {
            short8 b = *(const short8*)&WaT[col * DIN + kk * 32 + quad * 8];
            acc = __builtin_amdgcn_mfma_f32_16x16x32_bf16(a1[kk], b, acc, 0, 0, 0);
        }
        const float bias = ba[col];
#pragma unroll
        for (int r = 0; r < 4; ++r) {
            const float v = fmaxf(acc[r] + bias, 0.f);
            hidA[(m0 + quad * 4 + r) * SH + col] = f2b(v);
        }
    }
    __syncthreads();  // hidden rows span the wn-waves

    short8 a2[DH / 32];
#pragma unroll
    for (int kk = 0; kk < DH / 32; ++kk)
        a2[kk] = *(const short8*)&hidA[(m0 + l16) * SH + kk * 32 + quad * 8];
#pragma unroll
    for (int nt = 0; nt < DOUT / (16 * NSPLIT); ++nt) {
        const int col = wn * (DOUT / NSPLIT) + nt * 16 + l16;
        floatx4 acc = {0.f, 0.f, 0.f, 0.f};
#pragma unroll
        for (int kk = 0; kk < DH / 32; ++kk) {
            short8 b = *(const short8*)&WbT[col * DH + kk * 32 + quad * 8];
            acc = __builtin_amdgcn_mfma_f32_16x16x32_bf16(a2[kk], b, acc, 0, 0, 0);
        }
        const float bias = bb[col];
#pragma unroll
        for (int r = 0; r < 4; ++r) {
            const float v = fmaxf(acc[r] + bias, 0.f);
            const int grow = row0 + m0 + quad * 4 + r;
            if (grow < n_rows) {
                if (OUT_BF16)
                    ((unsigned short*)outp)[(size_t)grow * DOUT + col] = f2b(v);
                else
                    ((float*)outp)[(size_t)grow * DOUT + col] = v;
            }
        }
    }
}

extern "C" void kernel_launch(void* const* d_in, const int* in_sizes, int n_in,
                              void* d_out, int out_size, void* d_ws,
                              size_t ws_size, hipStream_t stream) {
    const float* x   = (const float*)d_in[0];
    const int*   ei  = (const int*)d_in[1];  // [2, N_EDGES] int32
    const float* W1a = (const float*)d_in[2];
    const float* b1a = (const float*)d_in[3];
    const float* W1b = (const float*)d_in[4];
    const float* b1b = (const float*)d_in[5];
    const float* W2a = (const float*)d_in[6];
    const float* b2a = (const float*)d_in[7];
    const float* W2b = (const float*)d_in[8];
    const float* b2b = (const float*)d_in[9];
    float* out = (float*)d_out;

    const int* src = ei;
    const int* dst = ei + N_EDGES;

    // Workspace: bf16 xb[N+1,64] h[N+1,128] (row N = zero sentinel) |
    //            bf16 weightsT | int deg/offpd/cursor/gcount | ushort nbr[pad]
    unsigned short* xb = (unsigned short*)d_ws;
    unsigned short* h  = xb + (size_t)(N_NODES + 1) * 64;
    unsigned short* W1aT = h + (size_t)(N_NODES + 1) * 128;
    unsigned short* W1bT = W1aT + 8192;
    unsigned short* W2aT = W1bT + 16384;
    unsigned short* W2bT = W2aT + 16384;
    int* deg    = (int*)(W2bT + 8192);
    int* offpd  = deg + N_NODES;
    int* cursor = offpd + N_NODES;
    int* gcount = cursor + N_NODES;
    unsigned short* nbr = (unsigned short*)(gcount + 64);

    constexpr int NB = (N_NODES + 1023) / 1024;  // 49 scan blocks
    constexpr int PREP_THREADS = 49152 + N_NODES * 16 + N_NODES + 24;

    // ---- Prep (weights + x convert + deg/gcount zero + sentinel rows) ----
    prep_kernel<<<(PREP_THREADS + 255) / 256, 256, 0, stream>>>(
        W1a, W1b, W2a, W2b, x, W1aT, W1bT, W2aT, W2bT, xb, h, deg, gcount);

    // ---- CSR build (padded to x4, rank-free) ----
    hist_kernel<<<(N_EDGES + 255) / 256, 256, 0, stream>>>(dst, deg, N_EDGES);
    offsets_kernel<<<NB, 1024, 0, stream>>>(deg, offpd, cursor, gcount, nbr,
                                            N_NODES);
    fill_kernel<<<(N_EDGES + 255) / 256, 256, 0, stream>>>(src, dst, cursor,
                                                           nbr, N_EDGES);

    // ---- Layer 1 (8-lane groups, 32 rows/block) ----
    gin_fused_kernel<64, 128, 128, true>
        <<<(N_NODES + 31) / 32, 256, 0, stream>>>(xb, offpd, nbr, W1aT, b1a,
                                                  W1bT, b1b, h, N_NODES);

    // ---- Layer 2 (16-lane groups, 16 rows/block) ----
    gin_fused_kernel<128, 128, 64, false>
        <<<(N_NODES + 15) / 16, 256, 0, stream>>>(h, offpd, nbr, W2aT, b2a,
                                                  W2bT, b2b, out, N_NODES);
}

// Round 11
// 216.972 us; speedup vs baseline: 1.1316x; 1.1316x over previous
//
#include <hip/hip_runtime.h>

#define N_NODES 50000
#define N_EDGES 800000

typedef __attribute__((ext_vector_type(8))) short short8;
typedef __attribute__((ext_vector_type(4))) float floatx4;

// float -> bf16 bits, round-to-nearest-even
static __device__ __forceinline__ unsigned short f2b(float f) {
    unsigned int u = __float_as_uint(f);
    unsigned int r = u + 0x7fffu + ((u >> 16) & 1u);
    return (unsigned short)(r >> 16);
}
static __device__ __forceinline__ unsigned int pk(float a, float b) {
    return (unsigned)f2b(a) | ((unsigned)f2b(b) << 16);
}
static __device__ __forceinline__ float blo(unsigned int u) {
    return __uint_as_float(u << 16);
}
static __device__ __forceinline__ float bhi(unsigned int u) {
    return __uint_as_float(u & 0xffff0000u);
}

// accumulate 4 bf16x8 rows into 8 fp32 lanes (same add tree as verified vers)
static __device__ __forceinline__ void acc4(float* f, uint4 v0, uint4 v1,
                                            uint4 v2, uint4 v3) {
    f[0] += (blo(v0.x) + blo(v1.x)) + (blo(v2.x) + blo(v3.x));
    f[1] += (bhi(v0.x) + bhi(v1.x)) + (bhi(v2.x) + bhi(v3.x));
    f[2] += (blo(v0.y) + blo(v1.y)) + (blo(v2.y) + blo(v3.y));
    f[3] += (bhi(v0.y) + bhi(v1.y)) + (bhi(v2.y) + bhi(v3.y));
    f[4] += (blo(v0.z) + blo(v1.z)) + (blo(v2.z) + blo(v3.z));
    f[5] += (bhi(v0.z) + bhi(v1.z)) + (bhi(v2.z) + bhi(v3.z));
    f[6] += (blo(v0.w) + blo(v1.w)) + (blo(v2.w) + blo(v3.w));
    f[7] += (bhi(v0.w) + bhi(v1.w)) + (bhi(v2.w) + bhi(v3.w));
}

// ---------------------------------------------------------------------------
// CSR build (R7-verified, 217.6us total): segments padded to x4, sentinel
// zero-row N_NODES. hist_rank: histogram + per-edge rank in one atomic.
// offsets: block-local scan + ONE atomicAdd per block for the base (offsets
// need not be monotone). fill: atomic-free fire-and-forget scatter.
// offpd = (off<<10 | padded_deg).
// R10 lesson: moving the atomic INTO fill (cursor variant) put the L2
// RMW-return latency on every edge's store path — regressed. Keep split.
// ---------------------------------------------------------------------------
__global__ void hist_rank_kernel(const int* __restrict__ dst,
                                 int* __restrict__ deg, int* __restrict__ rank,
                                 int n) {
    int i = blockIdx.x * blockDim.x + threadIdx.x;
    if (i < n) rank[i] = atomicAdd(&deg[dst[i]], 1);
}

__global__ __launch_bounds__(1024) void offsets_kernel(
    const int* __restrict__ deg, int* __restrict__ offpd,
    int* __restrict__ gcount, unsigned short* __restrict__ nbr, int n) {
    __shared__ int s[1024];
    __shared__ int base;
    const int tid = threadIdx.x;
    const int i = blockIdx.x * 1024 + tid;
    const int d = (i < n) ? deg[i] : 0;
    const int pd = (d + 3) & ~3;
    s[tid] = pd;
    __syncthreads();
    for (int o = 1; o < 1024; o <<= 1) {
        int t = (tid >= o) ? s[tid - o] : 0;
        __syncthreads();
        s[tid] += t;
        __syncthreads();
    }
    if (tid == 1023) base = atomicAdd(gcount, s[1023]);
    __syncthreads();
    const int excl = base + s[tid] - pd;
    if (i < n) {
        offpd[i] = (excl << 10) | pd;
        for (int k = d; k < pd; ++k) nbr[excl + k] = (unsigned short)N_NODES;
    }
}

// Atomic-free edge scatter: pos = off(dst) + rank.
__global__ void fill_kernel(const int* __restrict__ src,
                            const int* __restrict__ dst,
                            const int* __restrict__ rank,
                            const int* __restrict__ offpd,
                            unsigned short* __restrict__ nbr, int n) {
    int i = blockIdx.x * blockDim.x + threadIdx.x;
    if (i < n) nbr[(offpd[dst[i]] >> 10) + rank[i]] = (unsigned short)src[i];
}

// ---------------------------------------------------------------------------
// Fused prep: weight transpose->bf16 [N][K] + x fp32->bf16 + deg/gcount
// zeroing + zero sentinel rows of xb and h (row N_NODES of each table).
// ---------------------------------------------------------------------------
__global__ __launch_bounds__(256) void prep_kernel(
    const float* __restrict__ W1a, const float* __restrict__ W1b,
    const float* __restrict__ W2a, const float* __restrict__ W2b,
    const float* __restrict__ x, unsigned short* __restrict__ W1aT,
    unsigned short* __restrict__ W1bT, unsigned short* __restrict__ W2aT,
    unsigned short* __restrict__ W2bT, unsigned short* __restrict__ xb,
    unsigned short* __restrict__ h, int* __restrict__ deg,
    int* __restrict__ gcount) {
    int i = blockIdx.x * 256 + threadIdx.x;
    if (i < 8192) {                       // W1a [64][128] -> [128][64]
        int n = i >> 6, k = i & 63;
        W1aT[i] = f2b(W1a[k * 128 + n]);
    } else if (i < 24576) {               // W1b [128][128] -> [128][128]
        int j = i - 8192, n = j >> 7, k = j & 127;
        W1bT[j] = f2b(W1b[k * 128 + n]);
    } else if (i < 40960) {               // W2a [128][128] -> [128][128]
        int j = i - 24576, n = j >> 7, k = j & 127;
        W2aT[j] = f2b(W2a[k * 128 + n]);
    } else if (i < 49152) {               // W2b [128][64] -> [64][128]
        int j = i - 40960, n = j >> 7, k = j & 127;
        W2bT[j] = f2b(W2b[k * 64 + n]);
    } else if (i < 49152 + N_NODES * 16) {  // x convert: float4 -> 4x bf16
        int j = i - 49152;
        float4 v = ((const float4*)x)[j];
        uint2 o;
        o.x = pk(v.x, v.y);
        o.y = pk(v.z, v.w);
        ((uint2*)xb)[j] = o;
    } else if (i < 49152 + N_NODES * 16 + N_NODES) {  // zero deg (+gcount)
        int j = i - (49152 + N_NODES * 16);
        deg[j] = 0;
        if (j == 0) *gcount = 0;
    } else {  // zero sentinel rows: xb row N (128B), h row N (256B)
        int j = i - (49152 + N_NODES * 16 + N_NODES);
        uint4 z = {0u, 0u, 0u, 0u};
        if (j < 8)
            ((uint4*)(xb + (size_t)N_NODES * 64))[j] = z;
        else if (j < 24)
            ((uint4*)(h + (size_t)N_NODES * 128))[j - 8] = z;
    }
}

// ---------------------------------------------------------------------------
// Fused GIN layer (R7-verified geometry). LPR = DIN/8 lanes per row, each
// lane one uint4 (16B); indices as aligned uint2 (segments padded x4);
// 8 edges in flight per group. One offpd read gives segment base+length.
// MLP: ROWS=32 -> 2x2 wave split; ROWS=16 -> 1x4 (N-quarters).
// Gather floor evidence (R2-R10): occupancy x2 = null; instr-cut = +14us;
// global/local degree balance = null/negative; fused/pinned column slicing =
// negative. ~45us/layer = random L2/L3 row-service latency floor.
// ---------------------------------------------------------------------------
template <int DIN, int DH, int DOUT, bool OUT_BF16>
__global__ __launch_bounds__(256) void gin_fused_kernel(
    const unsigned short* __restrict__ xin, const int* __restrict__ offpd,
    const unsigned short* __restrict__ nbr,
    const unsigned short* __restrict__ WaT, const float* __restrict__ ba,
    const unsigned short* __restrict__ WbT, const float* __restrict__ bb,
    void* __restrict__ outp, int n_rows) {
    constexpr int LPR = DIN / 8;     // lanes per row (uint4 = 8 bf16 each)
    constexpr int ROWS = 256 / LPR;  // rows per block (32 or 16)
    constexpr int SA = DIN + 16;
    constexpr int SH = DH + 16;
    __shared__ __attribute__((aligned(16))) unsigned short tA[ROWS * SA];
    __shared__ __attribute__((aligned(16))) unsigned short hidA[ROWS * SH];

    const int tid = threadIdx.x;
    const int row0 = blockIdx.x * ROWS;
    const int grp = tid / LPR;  // one row per group
    const int c = tid % LPR;
    const int node = row0 + grp;

    // ---- gather phase ----
    float f[8] = {0.f, 0.f, 0.f, 0.f, 0.f, 0.f, 0.f, 0.f};
    const uint4* xr = (const uint4*)xin;
    if (node < n_rows) {
        const uint4 a = xr[(size_t)node * LPR + c];
        f[0] = blo(a.x); f[1] = bhi(a.x);
        f[2] = blo(a.y); f[3] = bhi(a.y);
        f[4] = blo(a.z); f[5] = bhi(a.z);
        f[6] = blo(a.w); f[7] = bhi(a.w);
        const int v = offpd[node];
        const int lo = v >> 10;
        const int hi = lo + (v & 1023);
        int j = lo;
        for (; j + 8 <= hi; j += 8) {
            const uint2 i0 = *(const uint2*)&nbr[j];
            const uint2 i1 = *(const uint2*)&nbr[j + 4];
            const int s0 = i0.x & 0xffff, s1 = i0.x >> 16;
            const int s2 = i0.y & 0xffff, s3 = i0.y >> 16;
            const int s4 = i1.x & 0xffff, s5 = i1.x >> 16;
            const int s6 = i1.y & 0xffff, s7 = i1.y >> 16;
            const uint4 v0 = xr[(size_t)s0 * LPR + c];
            const uint4 v1 = xr[(size_t)s1 * LPR + c];
            const uint4 v2 = xr[(size_t)s2 * LPR + c];
            const uint4 v3 = xr[(size_t)s3 * LPR + c];
            const uint4 v4 = xr[(size_t)s4 * LPR + c];
            const uint4 v5 = xr[(size_t)s5 * LPR + c];
            const uint4 v6 = xr[(size_t)s6 * LPR + c];
            const uint4 v7 = xr[(size_t)s7 * LPR + c];
            acc4(f, v0, v1, v2, v3);
            acc4(f, v4, v5, v6, v7);
        }
        if (j < hi) {  // exactly one 4-edge chunk remains (padding)
            const uint2 i0 = *(const uint2*)&nbr[j];
            const int s0 = i0.x & 0xffff, s1 = i0.x >> 16;
            const int s2 = i0.y & 0xffff, s3 = i0.y >> 16;
            const uint4 v0 = xr[(size_t)s0 * LPR + c];
            const uint4 v1 = xr[(size_t)s1 * LPR + c];
            const uint4 v2 = xr[(size_t)s2 * LPR + c];
            const uint4 v3 = xr[(size_t)s3 * LPR + c];
            acc4(f, v0, v1, v2, v3);
        }
    }
    uint4 o;
    o.x = pk(f[0], f[1]);
    o.y = pk(f[2], f[3]);
    o.z = pk(f[4], f[5]);
    o.w = pk(f[6], f[7]);
    *(uint4*)&tA[grp * SA + c * 8] = o;
    __syncthreads();

    // ---- MLP phase ----
    constexpr int MT = ROWS / 16;     // M tiles (2 or 1)
    constexpr int NSPLIT = 4 / MT;    // N split across waves (2 or 4)
    const int lane = tid & 63;
    const int wv = tid >> 6;
    const int wm = wv % MT;
    const int wn = wv / MT;
    const int quad = lane >> 4;
    const int l16 = lane & 15;
    const int m0 = wm * 16;

    short8 a1[DIN / 32];
#pragma unroll
    for (int kk = 0; kk < DIN / 32; ++kk)
        a1[kk] = *(const short8*)&tA[(m0 + l16) * SA + kk * 32 + quad * 8];
#pragma unroll
    for (int nt = 0; nt < DH / (16 * NSPLIT); ++nt) {
        const int col = wn * (DH / NSPLIT) + nt * 16 + l16;
        floatx4 acc = {0.f, 0.f, 0.f, 0.f};
#pragma unroll
        for (int kk = 0; kk < DIN / 32; ++kk) {
            short8 b = *(const short8*)&WaT[col * DIN + kk * 32 + quad * 8];
            acc = __builtin_amdgcn_mfma_f32_16x16x32_bf16(a1[kk], b, acc, 0, 0, 0);
        }
        const float bias = ba[col];
#pragma unroll
        for (int r = 0; r < 4; ++r) {
            const float v = fmaxf(acc[r] + bias, 0.f);
            hidA[(m0 + quad * 4 + r) * SH + col] = f2b(v);
        }
    }
    __syncthreads();  // hidden rows span the wn-waves

    short8 a2[DH / 32];
#pragma unroll
    for (int kk = 0; kk < DH / 32; ++kk)
        a2[kk] = *(const short8*)&hidA[(m0 + l16) * SH + kk * 32 + quad * 8];
#pragma unroll
    for (int nt = 0; nt < DOUT / (16 * NSPLIT); ++nt) {
        const int col = wn * (DOUT / NSPLIT) + nt * 16 + l16;
        floatx4 acc = {0.f, 0.f, 0.f, 0.f};
#pragma unroll
        for (int kk = 0; kk < DH / 32; ++kk) {
            short8 b = *(const short8*)&WbT[col * DH + kk * 32 + quad * 8];
            acc = __builtin_amdgcn_mfma_f32_16x16x32_bf16(a2[kk], b, acc, 0, 0, 0);
        }
        const float bias = bb[col];
#pragma unroll
        for (int r = 0; r < 4; ++r) {
            const float v = fmaxf(acc[r] + bias, 0.f);
            const int grow = row0 + m0 + quad * 4 + r;
            if (grow < n_rows) {
                if (OUT_BF16)
                    ((unsigned short*)outp)[(size_t)grow * DOUT + col] = f2b(v);
                else
                    ((float*)outp)[(size_t)grow * DOUT + col] = v;
            }
        }
    }
}

extern "C" void kernel_launch(void* const* d_in, const int* in_sizes, int n_in,
                              void* d_out, int out_size, void* d_ws,
                              size_t ws_size, hipStream_t stream) {
    const float* x   = (const float*)d_in[0];
    const int*   ei  = (const int*)d_in[1];  // [2, N_EDGES] int32
    const float* W1a = (const float*)d_in[2];
    const float* b1a = (const float*)d_in[3];
    const float* W1b = (const float*)d_in[4];
    const float* b1b = (const float*)d_in[5];
    const float* W2a = (const float*)d_in[6];
    const float* b2a = (const float*)d_in[7];
    const float* W2b = (const float*)d_in[8];
    const float* b2b = (const float*)d_in[9];
    float* out = (float*)d_out;

    const int* src = ei;
    const int* dst = ei + N_EDGES;

    // Workspace: bf16 xb[N+1,64] h[N+1,128] (row N = zero sentinel) |
    //            bf16 weightsT | int deg/offpd/gcount/rank | ushort nbr[pad]
    unsigned short* xb = (unsigned short*)d_ws;
    unsigned short* h  = xb + (size_t)(N_NODES + 1) * 64;
    unsigned short* W1aT = h + (size_t)(N_NODES + 1) * 128;
    unsigned short* W1bT = W1aT + 8192;
    unsigned short* W2aT = W1bT + 16384;
    unsigned short* W2bT = W2aT + 16384;
    int* deg    = (int*)(W2bT + 8192);
    int* offpd  = deg + N_NODES;
    int* gcount = offpd + N_NODES;
    int* rank   = gcount + 64;  // 64-int pad keeps alignment
    unsigned short* nbr = (unsigned short*)(rank + N_EDGES);

    constexpr int NB = (N_NODES + 1023) / 1024;  // 49 scan blocks
    constexpr int PREP_THREADS = 49152 + N_NODES * 16 + N_NODES + 24;

    // ---- Prep (weights + x convert + deg/gcount zero + sentinel rows) ----
    prep_kernel<<<(PREP_THREADS + 255) / 256, 256, 0, stream>>>(
        W1a, W1b, W2a, W2b, x, W1aT, W1bT, W2aT, W2bT, xb, h, deg, gcount);

    // ---- CSR build (padded to x4) ----
    hist_rank_kernel<<<(N_EDGES + 255) / 256, 256, 0, stream>>>(dst, deg, rank,
                                                                N_EDGES);
    offsets_kernel<<<NB, 1024, 0, stream>>>(deg, offpd, gcount, nbr, N_NODES);
    fill_kernel<<<(N_EDGES + 255) / 256, 256, 0, stream>>>(src, dst, rank,
                                                           offpd, nbr, N_EDGES);

    // ---- Layer 1 (8-lane groups, 32 rows/block) ----
    gin_fused_kernel<64, 128, 128, true>
        <<<(N_NODES + 31) / 32, 256, 0, stream>>>(xb, offpd, nbr, W1aT, b1a,
                                                  W1bT, b1b, h, N_NODES);

    // ---- Layer 2 (16-lane groups, 16 rows/block) ----
    gin_fused_kernel<128, 128, 64, false>
        <<<(N_NODES + 15) / 16, 256, 0, stream>>>(h, offpd, nbr, W2aT, b2a,
                                                  W2bT, b2b, out, N_NODES);
}